// Round 18
// baseline (179.990 us; speedup 1.0000x reference)
//
#include <hip/hip_runtime.h>

// ---------------------------------------------------------------------------
// GraphSAGE (max-pool SAGE x2 + edge heads), fp32 in/out, fp16 intermediates.
// Identity 1: relu((neigh*scale) @ W.T + b) = relu(scale*(neigh@W.T) + b)
//   -> pool matmul per-NODE (50k) not per-EDGE (1.6M).
// Identity 2: max seeded at 0 == relu'd max with empty->0.
// Round 17 resubmit (container infra failure): aggregate reworked to 2 EDGES
//   PER LOAD INST: lane = (channel-pair, edge-parity); each lane loads 4B
//   (2 fp16 ch) of its half's edge -> same 8-deep instruction window covers
//   16 edges in flight (2x MLP). Odd-tail via idx clamp (fmax idempotent ->
//   exact). Cross-half combine = shfl_xor(32); packed uint writes.
// ---------------------------------------------------------------------------

typedef _Float16 h16;
typedef __attribute__((ext_vector_type(4))) _Float16 h16x4;
typedef __attribute__((ext_vector_type(4))) float f32x4;
#define MFMA16(a, b, c) __builtin_amdgcn_mfma_f32_16x16x16f16(a, b, c, 0, 0, 0)

#define NBMAX 1600          // buckets of 32 nodes: ceil(50000/32)=1563
#define NFB   256           // blocks for hist/binfill (1 per CU)
#define HBT   1024          // threads for hist/binfill (16 waves)

union HU { unsigned u; h16 h[2]; };

// hist (per-block LDS histogram, both directions) + layer-1 pool matmul.
__global__ __launch_bounds__(HBT)
void histmm_kernel(const int* __restrict__ esrc,
                   const int* __restrict__ edst,
                   int* __restrict__ bucketTotal,
                   int* __restrict__ blockBase,
                   const float* __restrict__ X,
                   const float* __restrict__ W,
                   h16* __restrict__ Z,
                   int E, int NB, int ntiles) {
    __shared__ int cnt[NBMAX];
    const int tid = threadIdx.x;
    for (int b = tid; b < NB; b += blockDim.x) cnt[b] = 0;
    __syncthreads();
    const int chunk = (E + gridDim.x - 1) / gridDim.x;
    const int start = blockIdx.x * chunk;
    const int end = min(start + chunk, E);
    for (int e = start + (int)tid; e < end; e += blockDim.x) {
        const int s = esrc[e];
        const int d = edst[e];
        if (s != d) {
            atomicAdd(&cnt[d >> 5], 1);
            atomicAdd(&cnt[s >> 5], 1);
        }
    }
    __syncthreads();
    for (int b = tid; b < NB; b += blockDim.x)
        blockBase[(size_t)blockIdx.x * NB + b] = atomicAdd(&bucketTotal[b], cnt[b]);

    // ---- mm phase (independent of other blocks' hist) ----
    const int lane = tid & 63;
    const int c = lane & 15, q = lane >> 4;
    int wave = (int)((blockIdx.x * blockDim.x + tid) >> 6);
    const int nwaves = (int)((gridDim.x * blockDim.x) >> 6);
    h16x4 bf[4][4];
#pragma unroll
    for (int ct = 0; ct < 4; ++ct)
#pragma unroll
        for (int ks = 0; ks < 4; ++ks) {
            const float4 w4 = *(const float4*)(W + (ct * 16 + c) * 64 + ks * 16 + q * 4);
            bf[ct][ks] = (h16x4){(h16)w4.x, (h16)w4.y, (h16)w4.z, (h16)w4.w};
        }
    for (int t = wave; t < ntiles; t += nwaves) {
        const int n0 = t * 16;
        h16x4 af[4];
        const float* xr = X + (size_t)(n0 + c) * 64 + q * 4;
#pragma unroll
        for (int ks = 0; ks < 4; ++ks) {
            const float4 v = *(const float4*)(xr + ks * 16);
            af[ks] = (h16x4){(h16)v.x, (h16)v.y, (h16)v.z, (h16)v.w};
        }
        f32x4 acc[4];
#pragma unroll
        for (int ct = 0; ct < 4; ++ct) acc[ct] = (f32x4){0.f, 0.f, 0.f, 0.f};
#pragma unroll
        for (int ct = 0; ct < 4; ++ct)
#pragma unroll
            for (int ks = 0; ks < 4; ++ks)
                acc[ct] = MFMA16(af[ks], bf[ct][ks], acc[ct]);
#pragma unroll
        for (int ct = 0; ct < 4; ++ct)
#pragma unroll
            for (int m = 0; m < 4; ++m)
                Z[(size_t)(n0 + q * 4 + m) * 64 + ct * 16 + c] = (h16)acc[ct][m];
    }
}

// binfill with the bucket scan folded in (see R14/R15).
__global__ __launch_bounds__(HBT)
void binfill_kernel(const int* __restrict__ esrc,
                    const int* __restrict__ edst,
                    const float* __restrict__ ewt,
                    const int* __restrict__ bucketTotal,
                    int* __restrict__ bucketStart,
                    const int* __restrict__ blockBase,
                    unsigned* __restrict__ entries, int E, int NB) {
    __shared__ int sv[NBMAX];
    __shared__ int wls[16];
    const int tid = threadIdx.x;
    const int lane = tid & 63;
    const int wid = tid >> 6;            // 0..15
    for (int b = tid; b < NB; b += blockDim.x) sv[b] = bucketTotal[b];
    __syncthreads();
    const int CH = (NBMAX + HBT - 1) / HBT;
    const int lo = tid * CH, hi = min(lo + CH, NB);
    int sum = 0;
    for (int i = lo; i < hi; ++i) sum += sv[i];
    int x = sum;
#pragma unroll
    for (int off = 1; off < 64; off <<= 1) {
        int t = __shfl_up(x, off, 64);
        if (lane >= off) x += t;
    }
    if (lane == 63) wls[wid] = x;
    __syncthreads();
    int wof = 0;
    for (int w = 0; w < wid; ++w) wof += wls[w];
    int run = wof + x - sum;
    for (int i = lo; i < hi; ++i) { const int v = sv[i]; sv[i] = run; run += v; }
    __syncthreads();
    if (blockIdx.x == 0)
        for (int b = tid; b < NB; b += blockDim.x) bucketStart[b] = sv[b];
    for (int b = tid; b < NB; b += blockDim.x)
        sv[b] += blockBase[(size_t)blockIdx.x * NB + b];
    __syncthreads();
    const int chunk = (E + gridDim.x - 1) / gridDim.x;
    const int start = blockIdx.x * chunk;
    const int end = min(start + chunk, E);
    for (int e = start + (int)tid; e < end; e += blockDim.x) {
        const int s = esrc[e];
        const int d = edst[e];
        if (s != d) {
            const unsigned wq =
                (unsigned)fminf(ewt[e] * 2048.f + 0.5f, 2047.f) << 21;
            const int pd = atomicAdd(&sv[d >> 5], 1);
            entries[pd] = (unsigned)s | ((unsigned)(d & 31) << 16) | wq;
            const int ps = atomicAdd(&sv[s >> 5], 1);
            entries[ps] = (unsigned)d | ((unsigned)(s & 31) << 16) | wq;
        }
    }
}

// Block per bucket: counting sort by dstlocal within the bucket's segment.
__global__ void sortbucket_kernel(const int* __restrict__ bucketStart,
                                  const int* __restrict__ bucketTotal,
                                  const unsigned* __restrict__ in,
                                  unsigned* __restrict__ out,
                                  int* __restrict__ nodeBeg, int n, int NB) {
    __shared__ int bin[32];
    __shared__ int cur[32];
    const int bkt = blockIdx.x;
    const int beg = bucketStart[bkt];
    const int cnt = bucketTotal[bkt];
    if (threadIdx.x < 32) bin[threadIdx.x] = 0;
    __syncthreads();
    for (int i = threadIdx.x; i < cnt; i += blockDim.x)
        atomicAdd(&bin[(in[beg + i] >> 16) & 31u], 1);
    __syncthreads();
    if (threadIdx.x == 0) {
        int run = 0;
#pragma unroll
        for (int r = 0; r < 32; ++r) { cur[r] = run; run += bin[r]; }
    }
    __syncthreads();
    if (threadIdx.x < 32) {
        const int node = bkt * 32 + (int)threadIdx.x;
        if (node < n) nodeBeg[node] = beg + cur[threadIdx.x];
    }
    if (bkt == NB - 1 && threadIdx.x == 0) nodeBeg[n] = beg + cnt;
    __syncthreads();
    for (int i = threadIdx.x; i < cnt; i += blockDim.x) {
        const unsigned e = in[beg + i];
        const int pos = beg + atomicAdd(&cur[(e >> 16) & 31u], 1);
        out[pos] = e;
    }
}

// v = scale*z + pb per channel (fp32), fmax accumulate — 2 channels/lane.
#define WSTEP(eV, mLo, mHi)                                                    \
    {                                                                          \
        HU hu;                                                                 \
        hu.u = *(const unsigned*)(Z + (size_t)((eV) & 0xffffu) * 64 + 2 * cp); \
        const float sc = fmaf(coefq, (float)((eV) >> 21), 1.f);                \
        mLo = fmaxf(mLo, fmaf(sc, (float)hu.h[0], pbLo));                      \
        mHi = fmaxf(mHi, fmaf(sc, (float)hu.h[1], pbHi));                      \
    }
#define ENT(idx) \
    (unsigned)__builtin_nontemporal_load(entries + (idx))

// Wave per PAIR of nodes; lane = (channel-pair cp, edge-parity half).
// 2 edges per load instruction -> 16 edges in flight at 8-deep window.
__global__ void aggregateW_kernel(const int* __restrict__ nodeBeg,
                                  const unsigned* __restrict__ entries,
                                  const h16* __restrict__ Z,
                                  const float* __restrict__ pb,
                                  const float* __restrict__ coefp,
                                  h16* __restrict__ agg, int n) {
    const int lane = threadIdx.x & 63;
    const int cp = lane & 31;       // channel pair: channels 2cp, 2cp+1
    const int half = lane >> 5;     // edge parity
    int wave = (int)((blockIdx.x * blockDim.x + threadIdx.x) >> 6);
    const int nwaves = (int)((gridDim.x * blockDim.x) >> 6);
    const float coefq = coefp[0] * (1.f / 2048.f);
    const float pbLo = pb[2 * cp], pbHi = pb[2 * cp + 1];
    const int npairs = (n + 1) >> 1;
    for (int p = wave; p < npairs; p += nwaves) {
        const int dA = __builtin_amdgcn_readfirstlane(2 * p);
        const int dB = dA + 1;
        const int begA = nodeBeg[dA];
        const int endA = nodeBeg[dA + 1];
        int iB = endA, endB = endA;          // begB == endA (contiguous)
        if (dB < n) endB = nodeBeg[dB + 1];
        float mAl0 = 0.f, mAh0 = 0.f, mAl1 = 0.f, mAh1 = 0.f;
        float mAl2 = 0.f, mAh2 = 0.f, mAl3 = 0.f, mAh3 = 0.f;
        float mBl0 = 0.f, mBh0 = 0.f, mBl1 = 0.f, mBh1 = 0.f;
        float mBl2 = 0.f, mBh2 = 0.f, mBl3 = 0.f, mBh3 = 0.f;
        int iA = begA;
        // main: 8 edges per node per iteration (4 pair-insts each)
        while (iA + 8 <= endA && iB + 8 <= endB) {
            unsigned ea[4], eb[4];
#pragma unroll
            for (int j = 0; j < 4; ++j) ea[j] = ENT(iA + 2 * j + half);
#pragma unroll
            for (int j = 0; j < 4; ++j) eb[j] = ENT(iB + 2 * j + half);
            WSTEP(ea[0], mAl0, mAh0) WSTEP(ea[1], mAl1, mAh1)
            WSTEP(ea[2], mAl2, mAh2) WSTEP(ea[3], mAl3, mAh3)
            WSTEP(eb[0], mBl0, mBh0) WSTEP(eb[1], mBl1, mBh1)
            WSTEP(eb[2], mBl2, mBh2) WSTEP(eb[3], mBl3, mBh3)
            iA += 8; iB += 8;
        }
        // drain A
        for (; iA + 8 <= endA; iA += 8) {
            unsigned ea[4];
#pragma unroll
            for (int j = 0; j < 4; ++j) ea[j] = ENT(iA + 2 * j + half);
            WSTEP(ea[0], mAl0, mAh0) WSTEP(ea[1], mAl1, mAh1)
            WSTEP(ea[2], mAl2, mAh2) WSTEP(ea[3], mAl3, mAh3)
        }
        for (; iA + 2 <= endA; iA += 2) {
            const unsigned e = ENT(iA + half);
            WSTEP(e, mAl0, mAh0)
        }
        if (iA < endA) {                       // odd tail: both halves same edge
            const unsigned e = ENT(iA);        // (fmax idempotent -> exact)
            WSTEP(e, mAl0, mAh0)
        }
        // drain B
        for (; iB + 8 <= endB; iB += 8) {
            unsigned eb[4];
#pragma unroll
            for (int j = 0; j < 4; ++j) eb[j] = ENT(iB + 2 * j + half);
            WSTEP(eb[0], mBl0, mBh0) WSTEP(eb[1], mBl1, mBh1)
            WSTEP(eb[2], mBl2, mBh2) WSTEP(eb[3], mBl3, mBh3)
        }
        for (; iB + 2 <= endB; iB += 2) {
            const unsigned e = ENT(iB + half);
            WSTEP(e, mBl0, mBh0)
        }
        if (iB < endB) {
            const unsigned e = ENT(iB);
            WSTEP(e, mBl0, mBh0)
        }
        // combine 4 accumulators, then across halves (lane^32)
        float rAl = fmaxf(fmaxf(mAl0, mAl1), fmaxf(mAl2, mAl3));
        float rAh = fmaxf(fmaxf(mAh0, mAh1), fmaxf(mAh2, mAh3));
        float rBl = fmaxf(fmaxf(mBl0, mBl1), fmaxf(mBl2, mBl3));
        float rBh = fmaxf(fmaxf(mBh0, mBh1), fmaxf(mBh2, mBh3));
        rAl = fmaxf(rAl, __shfl_xor(rAl, 32, 64));
        rAh = fmaxf(rAh, __shfl_xor(rAh, 32, 64));
        rBl = fmaxf(rBl, __shfl_xor(rBl, 32, 64));
        rBh = fmaxf(rBh, __shfl_xor(rBh, 32, 64));
        if (half == 0) {
            HU oa; oa.h[0] = (h16)rAl; oa.h[1] = (h16)rAh;
            *(unsigned*)(agg + (size_t)dA * 64 + 2 * cp) = oa.u;
            if (dB < n) {
                HU ob; ob.h[0] = (h16)rBl; ob.h[1] = (h16)rBh;
                *(unsigned*)(agg + (size_t)dB * 64 + 2 * cp) = ob.u;
            }
        }
    }
}

// Fused layer-1 fin + layer-2 pool matmul:
// H1 = relu([X | AGG] @ f1w^T + b);  Z2 = H1 @ p2w^T  (same kernel).
__global__ __launch_bounds__(256, 2)
void finAmm_kernel(const float* __restrict__ XA, const h16* __restrict__ XB,
                   const float* __restrict__ W, const float* __restrict__ b,
                   const float* __restrict__ W2,
                   h16* __restrict__ H, h16* __restrict__ Z2, int ntiles) {
    __shared__ h16 ldsT[4][16 * 68];
    const int lane = threadIdx.x & 63;
    const int wid = threadIdx.x >> 6;
    const int c = lane & 15, q = lane >> 4;
    int wave = (int)((blockIdx.x * blockDim.x + threadIdx.x) >> 6);
    const int nwaves = (int)((gridDim.x * blockDim.x) >> 6);
    h16x4 bf[4][8], bf2[4][4];
#pragma unroll
    for (int ct = 0; ct < 4; ++ct) {
#pragma unroll
        for (int ks = 0; ks < 8; ++ks) {
            const float4 w4 = *(const float4*)(W + (ct * 16 + c) * 128 + ks * 16 + q * 4);
            bf[ct][ks] = (h16x4){(h16)w4.x, (h16)w4.y, (h16)w4.z, (h16)w4.w};
        }
#pragma unroll
        for (int ks = 0; ks < 4; ++ks) {
            const float4 w4 = *(const float4*)(W2 + (ct * 16 + c) * 64 + ks * 16 + q * 4);
            bf2[ct][ks] = (h16x4){(h16)w4.x, (h16)w4.y, (h16)w4.z, (h16)w4.w};
        }
    }
    float bc[4];
#pragma unroll
    for (int ct = 0; ct < 4; ++ct) bc[ct] = b[ct * 16 + c];
    for (int t = wave; t < ntiles; t += nwaves) {
        const int n0 = t * 16;
        h16x4 af[8];
        {
            const float* ra = XA + (size_t)(n0 + c) * 64 + q * 4;
#pragma unroll
            for (int ks = 0; ks < 4; ++ks) {
                const float4 v = *(const float4*)(ra + ks * 16);
                af[ks] = (h16x4){(h16)v.x, (h16)v.y, (h16)v.z, (h16)v.w};
            }
        }
        const h16* rb = XB + (size_t)(n0 + c) * 64 + q * 4;
#pragma unroll
        for (int ks = 0; ks < 4; ++ks) af[4 + ks] = *(const h16x4*)(rb + ks * 16);
        f32x4 acc[4];
#pragma unroll
        for (int ct = 0; ct < 4; ++ct) acc[ct] = (f32x4){bc[ct], bc[ct], bc[ct], bc[ct]};
#pragma unroll
        for (int ct = 0; ct < 4; ++ct)
#pragma unroll
            for (int ks = 0; ks < 8; ++ks)
                acc[ct] = MFMA16(af[ks], bf[ct][ks], acc[ct]);
#pragma unroll
        for (int ct = 0; ct < 4; ++ct)
#pragma unroll
            for (int m = 0; m < 4; ++m) {
                const h16 hv = (h16)fmaxf(acc[ct][m], 0.f);
                H[(size_t)(n0 + q * 4 + m) * 64 + ct * 16 + c] = hv;
                ldsT[wid][(q * 4 + m) * 68 + ct * 16 + c] = hv;
            }
        h16x4 af2[4];
#pragma unroll
        for (int ks = 0; ks < 4; ++ks)
            af2[ks] = *(const h16x4*)&ldsT[wid][c * 68 + ks * 16 + q * 4];
        f32x4 acc2[4];
#pragma unroll
        for (int ct = 0; ct < 4; ++ct) acc2[ct] = (f32x4){0.f, 0.f, 0.f, 0.f};
#pragma unroll
        for (int ct = 0; ct < 4; ++ct)
#pragma unroll
            for (int ks = 0; ks < 4; ++ks)
                acc2[ct] = MFMA16(af2[ks], bf2[ct][ks], acc2[ct]);
#pragma unroll
        for (int ct = 0; ct < 4; ++ct)
#pragma unroll
            for (int m = 0; m < 4; ++m)
                Z2[(size_t)(n0 + q * 4 + m) * 64 + ct * 16 + c] = (h16)acc2[ct][m];
    }
}

// Layer-2 fin + head projections fused; h2 never materialized.
__global__ __launch_bounds__(256, 2)
void fin2A_kernel(const h16* __restrict__ XA, const h16* __restrict__ XB,
                  const float* __restrict__ W, const float* __restrict__ b,
                  const float* __restrict__ ewp_w, const float* __restrict__ ep_w,
                  float4* __restrict__ nodeheads, int ntiles) {
    const int lane = threadIdx.x & 63;
    const int c = lane & 15, q = lane >> 4;
    int wave = (int)((blockIdx.x * blockDim.x + threadIdx.x) >> 6);
    const int nwaves = (int)((gridDim.x * blockDim.x) >> 6);
    h16x4 bf[4][8];
#pragma unroll
    for (int ct = 0; ct < 4; ++ct)
#pragma unroll
        for (int ks = 0; ks < 8; ++ks) {
            const float4 w4 = *(const float4*)(W + (ct * 16 + c) * 128 + ks * 16 + q * 4);
            bf[ct][ks] = (h16x4){(h16)w4.x, (h16)w4.y, (h16)w4.z, (h16)w4.w};
        }
    float bc[4], hw1s[4], hw1d[4], hw2s[4], hw2d[4];
#pragma unroll
    for (int ct = 0; ct < 4; ++ct) {
        bc[ct] = b[ct * 16 + c];
        hw1s[ct] = ewp_w[ct * 16 + c];
        hw1d[ct] = ewp_w[64 + ct * 16 + c];
        hw2s[ct] = ep_w[ct * 16 + c];
        hw2d[ct] = ep_w[64 + ct * 16 + c];
    }
    for (int t = wave; t < ntiles; t += nwaves) {
        const int n0 = t * 16;
        const h16* __restrict__ ra = XA + (size_t)(n0 + c) * 64 + q * 4;
        const h16* __restrict__ rb = XB + (size_t)(n0 + c) * 64 + q * 4;
        h16x4 af[8];
#pragma unroll
        for (int ks = 0; ks < 4; ++ks) {
            af[ks] = *(const h16x4*)(ra + ks * 16);
            af[4 + ks] = *(const h16x4*)(rb + ks * 16);
        }
        f32x4 acc[4];
#pragma unroll
        for (int ct = 0; ct < 4; ++ct) acc[ct] = (f32x4){bc[ct], bc[ct], bc[ct], bc[ct]};
#pragma unroll
        for (int ct = 0; ct < 4; ++ct)
#pragma unroll
            for (int ks = 0; ks < 8; ++ks)
                acc[ct] = MFMA16(af[ks], bf[ct][ks], acc[ct]);
        f32x4 r1 = {0.f, 0.f, 0.f, 0.f}, r2 = r1, r3 = r1, r4 = r1;
#pragma unroll
        for (int ct = 0; ct < 4; ++ct)
#pragma unroll
            for (int m = 0; m < 4; ++m) {
                const float h = fmaxf(acc[ct][m], 0.f);
                r1[m] = fmaf(hw1s[ct], h, r1[m]);
                r2[m] = fmaf(hw1d[ct], h, r2[m]);
                r3[m] = fmaf(hw2s[ct], h, r3[m]);
                r4[m] = fmaf(hw2d[ct], h, r4[m]);
            }
#pragma unroll
        for (int off = 1; off < 16; off <<= 1)
#pragma unroll
            for (int m = 0; m < 4; ++m) {
                r1[m] += __shfl_xor(r1[m], off, 16);
                r2[m] += __shfl_xor(r2[m], off, 16);
                r3[m] += __shfl_xor(r3[m], off, 16);
                r4[m] += __shfl_xor(r4[m], off, 16);
            }
        if (c == 0) {
#pragma unroll
            for (int m = 0; m < 4; ++m)
                nodeheads[n0 + q * 4 + m] =
                    make_float4(r1[m], r2[m], r3[m], r4[m]);
        }
    }
}

// Thread per prediction edge: 2x16 B gathers from the 0.8 MB per-node table.
__global__ void headsP_kernel(const int* __restrict__ psrc,
                              const int* __restrict__ pdst,
                              const float4* __restrict__ nodeheads,
                              const float* __restrict__ ewp_b,
                              const float* __restrict__ ep_b,
                              float* __restrict__ out, int P) {
    int t = blockIdx.x * blockDim.x + threadIdx.x;
    const int stride = gridDim.x * blockDim.x;
    const float b1 = ewp_b[0], b2 = ep_b[0];
    for (; t < P; t += stride) {
        const float4 qs = nodeheads[psrc[t]];
        const float4 qd = nodeheads[pdst[t]];
        out[t] = fmaxf(qs.x + qd.y + b1, 0.f);
        out[(size_t)P + t] = qs.z + qd.w + b2;
    }
}

extern "C" void kernel_launch(void* const* d_in, const int* in_sizes, int n_in,
                              void* d_out, int out_size, void* d_ws, size_t ws_size,
                              hipStream_t stream) {
    const float* x      = (const float*)d_in[0];
    const int*   pe     = (const int*)d_in[1];
    const int*   me     = (const int*)d_in[2];
    const float* mew    = (const float*)d_in[3];
    const float* coef1  = (const float*)d_in[4];
    const float* p1w    = (const float*)d_in[5];
    const float* p1b    = (const float*)d_in[6];
    const float* f1w    = (const float*)d_in[7];
    const float* f1b    = (const float*)d_in[8];
    const float* coef2  = (const float*)d_in[9];
    const float* p2w    = (const float*)d_in[10];
    const float* p2b    = (const float*)d_in[11];
    const float* f2w    = (const float*)d_in[12];
    const float* f2b    = (const float*)d_in[13];
    const float* ewp_w  = (const float*)d_in[14];
    const float* ewp_b  = (const float*)d_in[15];
    const float* ep_w   = (const float*)d_in[16];
    const float* ep_b   = (const float*)d_in[17];

    const int n = in_sizes[0] / 64;   // 50000 nodes
    const int P = in_sizes[1] / 2;    // 200000 prediction edges
    const int E = in_sizes[2] / 2;    // 800000 message edges
    const int NB = (n + 31) >> 5;     // 1563 buckets of 32 nodes
    const int ntiles = (n + 15) >> 4; // 3125 (exact: 50000 = 16*3125)

    // ws layout (~36 MB): nodeheads first for 16 B alignment.
    float4* nodeheads = (float4*)d_ws;                       // n
    h16* z16   = (h16*)(nodeheads + n);                      // n*64
    h16* agg16 = z16 + (size_t)n * 64;                       // n*64
    h16* h1    = agg16 + (size_t)n * 64;                     // n*64
    unsigned* entriesA = (unsigned*)(h1 + (size_t)n * 64);   // 2E (unsorted)
    unsigned* entriesB = entriesA + 2 * (size_t)E;           // 2E (dst-sorted)
    int* bucketTotal = (int*)(entriesB + 2 * (size_t)E);     // NBMAX
    int* bucketStart = bucketTotal + NBMAX;                  // NBMAX
    int* nodeBeg     = bucketStart + NBMAX;                  // n+1
    int* blockBase   = nodeBeg + (n + 1);                    // NFB*NB

    const int* esrc = me;
    const int* edst = me + E;
    const int* psrc = pe;
    const int* pdst = pe + P;

    const dim3 blk(256);
    const dim3 blkHB(HBT);
    const int mfGrid = (ntiles + 3) / 4;   // 782: 1 wave per 16-node tile
    const int agGrid = 2048;               // 8192 waves over 25k node pairs
    const int hpGrid = (P + 255) / 256;

    // ---- bucket build + dst-sort + layer-1 pool matmul ----
    hipMemsetAsync(bucketTotal, 0, (size_t)NB * sizeof(int), stream);
    histmm_kernel<<<NFB, blkHB, 0, stream>>>(esrc, edst, bucketTotal, blockBase,
                                             x, p1w, z16, E, NB, ntiles);
    binfill_kernel<<<NFB, blkHB, 0, stream>>>(esrc, edst, mew, bucketTotal,
                                              bucketStart, blockBase, entriesA, E, NB);
    sortbucket_kernel<<<NB, blk, 0, stream>>>(bucketStart, bucketTotal,
                                              entriesA, entriesB, nodeBeg, n, NB);

    // ---- layer 1 (+ fused layer-2 pool matmul) ----
    aggregateW_kernel<<<agGrid, blk, 0, stream>>>(nodeBeg, entriesB, z16,
                                                  p1b, coef1, agg16, n);
    finAmm_kernel<<<mfGrid, blk, 0, stream>>>(x, agg16, f1w, f1b, p2w,
                                              h1, z16, ntiles);

    // ---- layer 2 ----
    aggregateW_kernel<<<agGrid, blk, 0, stream>>>(nodeBeg, entriesB, z16,
                                                  p2b, coef2, agg16, n);
    fin2A_kernel<<<mfGrid, blk, 0, stream>>>(h1, agg16, f2w, f2b,
                                             ewp_w, ep_w, nodeheads, ntiles);

    // ---- edge heads ----
    headsP_kernel<<<hpGrid, blk, 0, stream>>>(psrc, pdst, nodeheads,
                                              ewp_b, ep_b, (float*)d_out, P);
}

// Round 19
// 166.088 us; speedup vs baseline: 1.0837x; 1.0837x over previous
//
#include <hip/hip_runtime.h>

// ---------------------------------------------------------------------------
// GraphSAGE (max-pool SAGE x2 + edge heads), fp32 in/out, fp16 intermediates.
// Identity 1: relu((neigh*scale) @ W.T + b) = relu(scale*(neigh@W.T) + b)
//   -> pool matmul per-NODE (50k) not per-EDGE (1.6M).
// Identity 2: max seeded at 0 == relu'd max with empty->0.
// Round 19: REVERT aggregate to R16's aggregateP (165.65us proven). R18's
//   2-edges-per-load variant regressed (166->180): L2 request count per edge
//   is line-bound (2x64B) regardless of lane mapping, and the split added
//   VALU + lost full-line coalescing. Gather is request-bound, not
//   instruction-window-bound.
// ---------------------------------------------------------------------------

typedef _Float16 h16;
typedef __attribute__((ext_vector_type(4))) _Float16 h16x4;
typedef __attribute__((ext_vector_type(4))) float f32x4;
#define MFMA16(a, b, c) __builtin_amdgcn_mfma_f32_16x16x16f16(a, b, c, 0, 0, 0)

#define NBMAX 1600          // buckets of 32 nodes: ceil(50000/32)=1563
#define NFB   256           // blocks for hist/binfill (1 per CU)
#define HBT   1024          // threads for hist/binfill (16 waves)

// hist (per-block LDS histogram, both directions) + layer-1 pool matmul.
__global__ __launch_bounds__(HBT)
void histmm_kernel(const int* __restrict__ esrc,
                   const int* __restrict__ edst,
                   int* __restrict__ bucketTotal,
                   int* __restrict__ blockBase,
                   const float* __restrict__ X,
                   const float* __restrict__ W,
                   h16* __restrict__ Z,
                   int E, int NB, int ntiles) {
    __shared__ int cnt[NBMAX];
    const int tid = threadIdx.x;
    for (int b = tid; b < NB; b += blockDim.x) cnt[b] = 0;
    __syncthreads();
    const int chunk = (E + gridDim.x - 1) / gridDim.x;
    const int start = blockIdx.x * chunk;
    const int end = min(start + chunk, E);
    for (int e = start + (int)tid; e < end; e += blockDim.x) {
        const int s = esrc[e];
        const int d = edst[e];
        if (s != d) {
            atomicAdd(&cnt[d >> 5], 1);
            atomicAdd(&cnt[s >> 5], 1);
        }
    }
    __syncthreads();
    for (int b = tid; b < NB; b += blockDim.x)
        blockBase[(size_t)blockIdx.x * NB + b] = atomicAdd(&bucketTotal[b], cnt[b]);

    // ---- mm phase (independent of other blocks' hist) ----
    const int lane = tid & 63;
    const int c = lane & 15, q = lane >> 4;
    int wave = (int)((blockIdx.x * blockDim.x + tid) >> 6);
    const int nwaves = (int)((gridDim.x * blockDim.x) >> 6);
    h16x4 bf[4][4];
#pragma unroll
    for (int ct = 0; ct < 4; ++ct)
#pragma unroll
        for (int ks = 0; ks < 4; ++ks) {
            const float4 w4 = *(const float4*)(W + (ct * 16 + c) * 64 + ks * 16 + q * 4);
            bf[ct][ks] = (h16x4){(h16)w4.x, (h16)w4.y, (h16)w4.z, (h16)w4.w};
        }
    for (int t = wave; t < ntiles; t += nwaves) {
        const int n0 = t * 16;
        h16x4 af[4];
        const float* xr = X + (size_t)(n0 + c) * 64 + q * 4;
#pragma unroll
        for (int ks = 0; ks < 4; ++ks) {
            const float4 v = *(const float4*)(xr + ks * 16);
            af[ks] = (h16x4){(h16)v.x, (h16)v.y, (h16)v.z, (h16)v.w};
        }
        f32x4 acc[4];
#pragma unroll
        for (int ct = 0; ct < 4; ++ct) acc[ct] = (f32x4){0.f, 0.f, 0.f, 0.f};
#pragma unroll
        for (int ct = 0; ct < 4; ++ct)
#pragma unroll
            for (int ks = 0; ks < 4; ++ks)
                acc[ct] = MFMA16(af[ks], bf[ct][ks], acc[ct]);
#pragma unroll
        for (int ct = 0; ct < 4; ++ct)
#pragma unroll
            for (int m = 0; m < 4; ++m)
                Z[(size_t)(n0 + q * 4 + m) * 64 + ct * 16 + c] = (h16)acc[ct][m];
    }
}

// binfill with the bucket scan folded in (see R14/R15).
__global__ __launch_bounds__(HBT)
void binfill_kernel(const int* __restrict__ esrc,
                    const int* __restrict__ edst,
                    const float* __restrict__ ewt,
                    const int* __restrict__ bucketTotal,
                    int* __restrict__ bucketStart,
                    const int* __restrict__ blockBase,
                    unsigned* __restrict__ entries, int E, int NB) {
    __shared__ int sv[NBMAX];
    __shared__ int wls[16];
    const int tid = threadIdx.x;
    const int lane = tid & 63;
    const int wid = tid >> 6;            // 0..15
    for (int b = tid; b < NB; b += blockDim.x) sv[b] = bucketTotal[b];
    __syncthreads();
    const int CH = (NBMAX + HBT - 1) / HBT;
    const int lo = tid * CH, hi = min(lo + CH, NB);
    int sum = 0;
    for (int i = lo; i < hi; ++i) sum += sv[i];
    int x = sum;
#pragma unroll
    for (int off = 1; off < 64; off <<= 1) {
        int t = __shfl_up(x, off, 64);
        if (lane >= off) x += t;
    }
    if (lane == 63) wls[wid] = x;
    __syncthreads();
    int wof = 0;
    for (int w = 0; w < wid; ++w) wof += wls[w];
    int run = wof + x - sum;
    for (int i = lo; i < hi; ++i) { const int v = sv[i]; sv[i] = run; run += v; }
    __syncthreads();
    if (blockIdx.x == 0)
        for (int b = tid; b < NB; b += blockDim.x) bucketStart[b] = sv[b];
    for (int b = tid; b < NB; b += blockDim.x)
        sv[b] += blockBase[(size_t)blockIdx.x * NB + b];
    __syncthreads();
    const int chunk = (E + gridDim.x - 1) / gridDim.x;
    const int start = blockIdx.x * chunk;
    const int end = min(start + chunk, E);
    for (int e = start + (int)tid; e < end; e += blockDim.x) {
        const int s = esrc[e];
        const int d = edst[e];
        if (s != d) {
            const unsigned wq =
                (unsigned)fminf(ewt[e] * 2048.f + 0.5f, 2047.f) << 21;
            const int pd = atomicAdd(&sv[d >> 5], 1);
            entries[pd] = (unsigned)s | ((unsigned)(d & 31) << 16) | wq;
            const int ps = atomicAdd(&sv[s >> 5], 1);
            entries[ps] = (unsigned)d | ((unsigned)(s & 31) << 16) | wq;
        }
    }
}

// Block per bucket: counting sort by dstlocal within the bucket's segment.
__global__ void sortbucket_kernel(const int* __restrict__ bucketStart,
                                  const int* __restrict__ bucketTotal,
                                  const unsigned* __restrict__ in,
                                  unsigned* __restrict__ out,
                                  int* __restrict__ nodeBeg, int n, int NB) {
    __shared__ int bin[32];
    __shared__ int cur[32];
    const int bkt = blockIdx.x;
    const int beg = bucketStart[bkt];
    const int cnt = bucketTotal[bkt];
    if (threadIdx.x < 32) bin[threadIdx.x] = 0;
    __syncthreads();
    for (int i = threadIdx.x; i < cnt; i += blockDim.x)
        atomicAdd(&bin[(in[beg + i] >> 16) & 31u], 1);
    __syncthreads();
    if (threadIdx.x == 0) {
        int run = 0;
#pragma unroll
        for (int r = 0; r < 32; ++r) { cur[r] = run; run += bin[r]; }
    }
    __syncthreads();
    if (threadIdx.x < 32) {
        const int node = bkt * 32 + (int)threadIdx.x;
        if (node < n) nodeBeg[node] = beg + cur[threadIdx.x];
    }
    if (bkt == NB - 1 && threadIdx.x == 0) nodeBeg[n] = beg + cnt;
    __syncthreads();
    for (int i = threadIdx.x; i < cnt; i += blockDim.x) {
        const unsigned e = in[beg + i];
        const int pos = beg + atomicAdd(&cur[(e >> 16) & 31u], 1);
        out[pos] = e;
    }
}

#define EDGE_STEP(eV, mV)                                                      \
    {                                                                          \
        const float zv = (float)Z[(size_t)((eV) & 0xffffu) * 64 + lane];       \
        mV = fmaxf(mV, fmaf(fmaf(coefq, (float)((eV) >> 21), 1.f), zv, pbc));  \
    }
#define RFL_NT(idx) \
    (unsigned)__builtin_amdgcn_readfirstlane((int)__builtin_nontemporal_load(entries + (idx)))

// Wave per PAIR of nodes (contiguous entry runs): 8-deep unroll per node ->
// 16 z-loads in flight. NT entry loads (streamed once; preserve z in L2).
__global__ void aggregateP_kernel(const int* __restrict__ nodeBeg,
                                  const unsigned* __restrict__ entries,
                                  const h16* __restrict__ Z,
                                  const float* __restrict__ pb,
                                  const float* __restrict__ coefp,
                                  h16* __restrict__ agg, int n) {
    const int lane = threadIdx.x & 63;
    int wave = (int)((blockIdx.x * blockDim.x + threadIdx.x) >> 6);
    const int nwaves = (int)((gridDim.x * blockDim.x) >> 6);
    const float coefq = coefp[0] * (1.f / 2048.f);
    const float pbc = pb[lane];
    const int npairs = (n + 1) >> 1;
    for (int p = wave; p < npairs; p += nwaves) {
        const int dA = __builtin_amdgcn_readfirstlane(2 * p);
        const int dB = dA + 1;
        const int begA = nodeBeg[dA];
        const int endA = nodeBeg[dA + 1];
        int iB = endA, endB = endA;          // begB == endA (contiguous)
        if (dB < n) endB = nodeBeg[dB + 1];
        float mA0 = 0.f, mA1 = 0.f, mA2 = 0.f, mA3 = 0.f;
        float mB0 = 0.f, mB1 = 0.f, mB2 = 0.f, mB3 = 0.f;
        int iA = begA;
        while (iA + 8 <= endA && iB + 8 <= endB) {
            unsigned ea[8], eb[8];
#pragma unroll
            for (int j = 0; j < 8; ++j) ea[j] = RFL_NT(iA + j);
#pragma unroll
            for (int j = 0; j < 8; ++j) eb[j] = RFL_NT(iB + j);
            EDGE_STEP(ea[0], mA0) EDGE_STEP(ea[1], mA1)
            EDGE_STEP(ea[2], mA2) EDGE_STEP(ea[3], mA3)
            EDGE_STEP(ea[4], mA0) EDGE_STEP(ea[5], mA1)
            EDGE_STEP(ea[6], mA2) EDGE_STEP(ea[7], mA3)
            EDGE_STEP(eb[0], mB0) EDGE_STEP(eb[1], mB1)
            EDGE_STEP(eb[2], mB2) EDGE_STEP(eb[3], mB3)
            EDGE_STEP(eb[4], mB0) EDGE_STEP(eb[5], mB1)
            EDGE_STEP(eb[6], mB2) EDGE_STEP(eb[7], mB3)
            iA += 8; iB += 8;
        }
        for (; iA + 4 <= endA; iA += 4) {
            unsigned ea[4];
#pragma unroll
            for (int j = 0; j < 4; ++j) ea[j] = RFL_NT(iA + j);
            EDGE_STEP(ea[0], mA0) EDGE_STEP(ea[1], mA1)
            EDGE_STEP(ea[2], mA2) EDGE_STEP(ea[3], mA3)
        }
        for (; iB + 4 <= endB; iB += 4) {
            unsigned eb[4];
#pragma unroll
            for (int j = 0; j < 4; ++j) eb[j] = RFL_NT(iB + j);
            EDGE_STEP(eb[0], mB0) EDGE_STEP(eb[1], mB1)
            EDGE_STEP(eb[2], mB2) EDGE_STEP(eb[3], mB3)
        }
        for (; iA < endA; ++iA) {
            const unsigned a0 = RFL_NT(iA);
            EDGE_STEP(a0, mA0)
        }
        for (; iB < endB; ++iB) {
            const unsigned b0 = RFL_NT(iB);
            EDGE_STEP(b0, mB0)
        }
        agg[(size_t)dA * 64 + lane] = (h16)fmaxf(fmaxf(mA0, mA1), fmaxf(mA2, mA3));
        if (dB < n)
            agg[(size_t)dB * 64 + lane] = (h16)fmaxf(fmaxf(mB0, mB1), fmaxf(mB2, mB3));
    }
}

// Fused layer-1 fin + layer-2 pool matmul:
// H1 = relu([X | AGG] @ f1w^T + b);  Z2 = H1 @ p2w^T  (same kernel).
__global__ __launch_bounds__(256, 2)
void finAmm_kernel(const float* __restrict__ XA, const h16* __restrict__ XB,
                   const float* __restrict__ W, const float* __restrict__ b,
                   const float* __restrict__ W2,
                   h16* __restrict__ H, h16* __restrict__ Z2, int ntiles) {
    __shared__ h16 ldsT[4][16 * 68];
    const int lane = threadIdx.x & 63;
    const int wid = threadIdx.x >> 6;
    const int c = lane & 15, q = lane >> 4;
    int wave = (int)((blockIdx.x * blockDim.x + threadIdx.x) >> 6);
    const int nwaves = (int)((gridDim.x * blockDim.x) >> 6);
    h16x4 bf[4][8], bf2[4][4];
#pragma unroll
    for (int ct = 0; ct < 4; ++ct) {
#pragma unroll
        for (int ks = 0; ks < 8; ++ks) {
            const float4 w4 = *(const float4*)(W + (ct * 16 + c) * 128 + ks * 16 + q * 4);
            bf[ct][ks] = (h16x4){(h16)w4.x, (h16)w4.y, (h16)w4.z, (h16)w4.w};
        }
#pragma unroll
        for (int ks = 0; ks < 4; ++ks) {
            const float4 w4 = *(const float4*)(W2 + (ct * 16 + c) * 64 + ks * 16 + q * 4);
            bf2[ct][ks] = (h16x4){(h16)w4.x, (h16)w4.y, (h16)w4.z, (h16)w4.w};
        }
    }
    float bc[4];
#pragma unroll
    for (int ct = 0; ct < 4; ++ct) bc[ct] = b[ct * 16 + c];
    for (int t = wave; t < ntiles; t += nwaves) {
        const int n0 = t * 16;
        h16x4 af[8];
        {
            const float* ra = XA + (size_t)(n0 + c) * 64 + q * 4;
#pragma unroll
            for (int ks = 0; ks < 4; ++ks) {
                const float4 v = *(const float4*)(ra + ks * 16);
                af[ks] = (h16x4){(h16)v.x, (h16)v.y, (h16)v.z, (h16)v.w};
            }
        }
        const h16* rb = XB + (size_t)(n0 + c) * 64 + q * 4;
#pragma unroll
        for (int ks = 0; ks < 4; ++ks) af[4 + ks] = *(const h16x4*)(rb + ks * 16);
        f32x4 acc[4];
#pragma unroll
        for (int ct = 0; ct < 4; ++ct) acc[ct] = (f32x4){bc[ct], bc[ct], bc[ct], bc[ct]};
#pragma unroll
        for (int ct = 0; ct < 4; ++ct)
#pragma unroll
            for (int ks = 0; ks < 8; ++ks)
                acc[ct] = MFMA16(af[ks], bf[ct][ks], acc[ct]);
#pragma unroll
        for (int ct = 0; ct < 4; ++ct)
#pragma unroll
            for (int m = 0; m < 4; ++m) {
                const h16 hv = (h16)fmaxf(acc[ct][m], 0.f);
                H[(size_t)(n0 + q * 4 + m) * 64 + ct * 16 + c] = hv;
                ldsT[wid][(q * 4 + m) * 68 + ct * 16 + c] = hv;
            }
        h16x4 af2[4];
#pragma unroll
        for (int ks = 0; ks < 4; ++ks)
            af2[ks] = *(const h16x4*)&ldsT[wid][c * 68 + ks * 16 + q * 4];
        f32x4 acc2[4];
#pragma unroll
        for (int ct = 0; ct < 4; ++ct) acc2[ct] = (f32x4){0.f, 0.f, 0.f, 0.f};
#pragma unroll
        for (int ct = 0; ct < 4; ++ct)
#pragma unroll
            for (int ks = 0; ks < 4; ++ks)
                acc2[ct] = MFMA16(af2[ks], bf2[ct][ks], acc2[ct]);
#pragma unroll
        for (int ct = 0; ct < 4; ++ct)
#pragma unroll
            for (int m = 0; m < 4; ++m)
                Z2[(size_t)(n0 + q * 4 + m) * 64 + ct * 16 + c] = (h16)acc2[ct][m];
    }
}

// Layer-2 fin + head projections fused; h2 never materialized.
__global__ __launch_bounds__(256, 2)
void fin2A_kernel(const h16* __restrict__ XA, const h16* __restrict__ XB,
                  const float* __restrict__ W, const float* __restrict__ b,
                  const float* __restrict__ ewp_w, const float* __restrict__ ep_w,
                  float4* __restrict__ nodeheads, int ntiles) {
    const int lane = threadIdx.x & 63;
    const int c = lane & 15, q = lane >> 4;
    int wave = (int)((blockIdx.x * blockDim.x + threadIdx.x) >> 6);
    const int nwaves = (int)((gridDim.x * blockDim.x) >> 6);
    h16x4 bf[4][8];
#pragma unroll
    for (int ct = 0; ct < 4; ++ct)
#pragma unroll
        for (int ks = 0; ks < 8; ++ks) {
            const float4 w4 = *(const float4*)(W + (ct * 16 + c) * 128 + ks * 16 + q * 4);
            bf[ct][ks] = (h16x4){(h16)w4.x, (h16)w4.y, (h16)w4.z, (h16)w4.w};
        }
    float bc[4], hw1s[4], hw1d[4], hw2s[4], hw2d[4];
#pragma unroll
    for (int ct = 0; ct < 4; ++ct) {
        bc[ct] = b[ct * 16 + c];
        hw1s[ct] = ewp_w[ct * 16 + c];
        hw1d[ct] = ewp_w[64 + ct * 16 + c];
        hw2s[ct] = ep_w[ct * 16 + c];
        hw2d[ct] = ep_w[64 + ct * 16 + c];
    }
    for (int t = wave; t < ntiles; t += nwaves) {
        const int n0 = t * 16;
        const h16* __restrict__ ra = XA + (size_t)(n0 + c) * 64 + q * 4;
        const h16* __restrict__ rb = XB + (size_t)(n0 + c) * 64 + q * 4;
        h16x4 af[8];
#pragma unroll
        for (int ks = 0; ks < 4; ++ks) {
            af[ks] = *(const h16x4*)(ra + ks * 16);
            af[4 + ks] = *(const h16x4*)(rb + ks * 16);
        }
        f32x4 acc[4];
#pragma unroll
        for (int ct = 0; ct < 4; ++ct) acc[ct] = (f32x4){bc[ct], bc[ct], bc[ct], bc[ct]};
#pragma unroll
        for (int ct = 0; ct < 4; ++ct)
#pragma unroll
            for (int ks = 0; ks < 8; ++ks)
                acc[ct] = MFMA16(af[ks], bf[ct][ks], acc[ct]);
        f32x4 r1 = {0.f, 0.f, 0.f, 0.f}, r2 = r1, r3 = r1, r4 = r1;
#pragma unroll
        for (int ct = 0; ct < 4; ++ct)
#pragma unroll
            for (int m = 0; m < 4; ++m) {
                const float h = fmaxf(acc[ct][m], 0.f);
                r1[m] = fmaf(hw1s[ct], h, r1[m]);
                r2[m] = fmaf(hw1d[ct], h, r2[m]);
                r3[m] = fmaf(hw2s[ct], h, r3[m]);
                r4[m] = fmaf(hw2d[ct], h, r4[m]);
            }
#pragma unroll
        for (int off = 1; off < 16; off <<= 1)
#pragma unroll
            for (int m = 0; m < 4; ++m) {
                r1[m] += __shfl_xor(r1[m], off, 16);
                r2[m] += __shfl_xor(r2[m], off, 16);
                r3[m] += __shfl_xor(r3[m], off, 16);
                r4[m] += __shfl_xor(r4[m], off, 16);
            }
        if (c == 0) {
#pragma unroll
            for (int m = 0; m < 4; ++m)
                nodeheads[n0 + q * 4 + m] =
                    make_float4(r1[m], r2[m], r3[m], r4[m]);
        }
    }
}

// Thread per prediction edge: 2x16 B gathers from the 0.8 MB per-node table.
__global__ void headsP_kernel(const int* __restrict__ psrc,
                              const int* __restrict__ pdst,
                              const float4* __restrict__ nodeheads,
                              const float* __restrict__ ewp_b,
                              const float* __restrict__ ep_b,
                              float* __restrict__ out, int P) {
    int t = blockIdx.x * blockDim.x + threadIdx.x;
    const int stride = gridDim.x * blockDim.x;
    const float b1 = ewp_b[0], b2 = ep_b[0];
    for (; t < P; t += stride) {
        const float4 qs = nodeheads[psrc[t]];
        const float4 qd = nodeheads[pdst[t]];
        out[t] = fmaxf(qs.x + qd.y + b1, 0.f);
        out[(size_t)P + t] = qs.z + qd.w + b2;
    }
}

extern "C" void kernel_launch(void* const* d_in, const int* in_sizes, int n_in,
                              void* d_out, int out_size, void* d_ws, size_t ws_size,
                              hipStream_t stream) {
    const float* x      = (const float*)d_in[0];
    const int*   pe     = (const int*)d_in[1];
    const int*   me     = (const int*)d_in[2];
    const float* mew    = (const float*)d_in[3];
    const float* coef1  = (const float*)d_in[4];
    const float* p1w    = (const float*)d_in[5];
    const float* p1b    = (const float*)d_in[6];
    const float* f1w    = (const float*)d_in[7];
    const float* f1b    = (const float*)d_in[8];
    const float* coef2  = (const float*)d_in[9];
    const float* p2w    = (const float*)d_in[10];
    const float* p2b    = (const float*)d_in[11];
    const float* f2w    = (const float*)d_in[12];
    const float* f2b    = (const float*)d_in[13];
    const float* ewp_w  = (const float*)d_in[14];
    const float* ewp_b  = (const float*)d_in[15];
    const float* ep_w   = (const float*)d_in[16];
    const float* ep_b   = (const float*)d_in[17];

    const int n = in_sizes[0] / 64;   // 50000 nodes
    const int P = in_sizes[1] / 2;    // 200000 prediction edges
    const int E = in_sizes[2] / 2;    // 800000 message edges
    const int NB = (n + 31) >> 5;     // 1563 buckets of 32 nodes
    const int ntiles = (n + 15) >> 4; // 3125 (exact: 50000 = 16*3125)

    // ws layout (~36 MB): nodeheads first for 16 B alignment.
    float4* nodeheads = (float4*)d_ws;                       // n
    h16* z16   = (h16*)(nodeheads + n);                      // n*64
    h16* agg16 = z16 + (size_t)n * 64;                       // n*64
    h16* h1    = agg16 + (size_t)n * 64;                     // n*64
    unsigned* entriesA = (unsigned*)(h1 + (size_t)n * 64);   // 2E (unsorted)
    unsigned* entriesB = entriesA + 2 * (size_t)E;           // 2E (dst-sorted)
    int* bucketTotal = (int*)(entriesB + 2 * (size_t)E);     // NBMAX
    int* bucketStart = bucketTotal + NBMAX;                  // NBMAX
    int* nodeBeg     = bucketStart + NBMAX;                  // n+1
    int* blockBase   = nodeBeg + (n + 1);                    // NFB*NB

    const int* esrc = me;
    const int* edst = me + E;
    const int* psrc = pe;
    const int* pdst = pe + P;

    const dim3 blk(256);
    const dim3 blkHB(HBT);
    const int mfGrid = (ntiles + 3) / 4;   // 782: 1 wave per 16-node tile
    const int agGrid = 2048;               // 8192 waves over 25k node pairs
    const int hpGrid = (P + 255) / 256;

    // ---- bucket build + dst-sort + layer-1 pool matmul ----
    hipMemsetAsync(bucketTotal, 0, (size_t)NB * sizeof(int), stream);
    histmm_kernel<<<NFB, blkHB, 0, stream>>>(esrc, edst, bucketTotal, blockBase,
                                             x, p1w, z16, E, NB, ntiles);
    binfill_kernel<<<NFB, blkHB, 0, stream>>>(esrc, edst, mew, bucketTotal,
                                              bucketStart, blockBase, entriesA, E, NB);
    sortbucket_kernel<<<NB, blk, 0, stream>>>(bucketStart, bucketTotal,
                                              entriesA, entriesB, nodeBeg, n, NB);

    // ---- layer 1 (+ fused layer-2 pool matmul) ----
    aggregateP_kernel<<<agGrid, blk, 0, stream>>>(nodeBeg, entriesB, z16,
                                                  p1b, coef1, agg16, n);
    finAmm_kernel<<<mfGrid, blk, 0, stream>>>(x, agg16, f1w, f1b, p2w,
                                              h1, z16, ntiles);

    // ---- layer 2 ----
    aggregateP_kernel<<<agGrid, blk, 0, stream>>>(nodeBeg, entriesB, z16,
                                                  p2b, coef2, agg16, n);
    fin2A_kernel<<<mfGrid, blk, 0, stream>>>(h1, agg16, f2w, f2b,
                                             ewp_w, ep_w, nodeheads, ntiles);

    // ---- edge heads ----
    headsP_kernel<<<hpGrid, blk, 0, stream>>>(psrc, pdst, nodeheads,
                                              ewp_b, ep_b, (float*)d_out, P);
}